// Round 11
// baseline (313.521 us; speedup 1.0000x reference)
//
#include <hip/hip_runtime.h>
#include <stdint.h>

#define Bn 2
#define Sn 2048
#define Dn 1024
#define Hn 16
#define DKn 64
#define EDn 256

typedef __attribute__((ext_vector_type(8))) short bvec8;   // 8 bf16 (4 VGPR)
typedef __attribute__((ext_vector_type(4))) float fvec4;   // 4 fp32 acc

#define MFMA(a, b, c) __builtin_amdgcn_mfma_f32_16x16x32_bf16(a, b, c, 0, 0, 0)

__device__ __forceinline__ float b2f(unsigned short u) {
  return __uint_as_float(((unsigned)u) << 16);
}
__device__ __forceinline__ unsigned short f2b(float x) {
  unsigned u = __float_as_uint(x);
  u += 0x7fffu + ((u >> 16) & 1u);
  return (unsigned short)(u >> 16);
}
// async global->LDS, 16B/lane; LDS dest is wave-uniform base + lane*16
__device__ __forceinline__ void g2l(const unsigned short* g, unsigned short* l) {
  __builtin_amdgcn_global_load_lds(
      (const __attribute__((address_space(1))) void*)g,
      (__attribute__((address_space(3))) void*)l, 16, 0, 0);
}
// 16-lane butterfly sum via DPP (xor 15,7,3,1) - pure VALU, no DS latency.
__device__ __forceinline__ int dpp_sum16(int x) {
  x += __builtin_amdgcn_update_dpp(0, x, 0x140, 0xf, 0xf, true);
  x += __builtin_amdgcn_update_dpp(0, x, 0x141, 0xf, 0xf, true);
  x += __builtin_amdgcn_update_dpp(0, x, 0x1B, 0xf, 0xf, true);
  x += __builtin_amdgcn_update_dpp(0, x, 0xB1, 0xf, 0xf, true);
  return x;
}
__device__ __forceinline__ unsigned dpp_umax16(unsigned x) {
  unsigned t;
  t = (unsigned)__builtin_amdgcn_update_dpp(0, (int)x, 0x140, 0xf, 0xf, true);
  x = x > t ? x : t;
  t = (unsigned)__builtin_amdgcn_update_dpp(0, (int)x, 0x141, 0xf, 0xf, true);
  x = x > t ? x : t;
  t = (unsigned)__builtin_amdgcn_update_dpp(0, (int)x, 0x1B, 0xf, 0xf, true);
  x = x > t ? x : t;
  t = (unsigned)__builtin_amdgcn_update_dpp(0, (int)x, 0xB1, 0xf, 0xf, true);
  x = x > t ? x : t;
  return x;
}

// ---------------- alphas: 0.05/(1+||.||_F) ----------------
__global__ __launch_bounds__(256) void k_alphas(
    const float* __restrict__ traces, const float* __restrict__ vtr,
    float* __restrict__ alphas) {
  int blk = blockIdx.x;
  const float* base;
  int n;
  if (blk < 16) { base = traces + blk * DKn * DKn; n = DKn * DKn; }
  else          { base = vtr + (blk - 16) * EDn * DKn; n = EDn * DKn; }
  float s = 0.f;
  for (int i = threadIdx.x; i < n; i += 256) { float v = base[i]; s += v * v; }
  __shared__ float red[256];
  red[threadIdx.x] = s;
  __syncthreads();
  for (int off = 128; off > 0; off >>= 1) {
    if (threadIdx.x < off) red[threadIdx.x] += red[threadIdx.x + off];
    __syncthreads();
  }
  if (threadIdx.x == 0) alphas[blk] = 0.05f / (1.f + sqrtf(red[0]));
}

// ---------------- prepass: W^T -> bf16  (Wt[n][k] = W[k][n]) ----------------
__global__ __launch_bounds__(256) void k_trW(
    const float* __restrict__ w0, const float* __restrict__ w1,
    const float* __restrict__ w2, const float* __restrict__ w3,
    unsigned short* __restrict__ dst) {
  int z = blockIdx.z;
  const float* src = (z == 0) ? w0 : ((z == 1) ? w1 : ((z == 2) ? w2 : w3));
  unsigned short* d = dst + (size_t)z * Dn * Dn;
  __shared__ unsigned short Tl[64][72];
  int tid = threadIdx.x;
  int k0 = blockIdx.y * 64, n0 = blockIdx.x * 64;
#pragma unroll
  for (int i = 0; i < 4; ++i) {
    int q = tid + 256 * i;
    int kr = q >> 4, c4 = q & 15;
    float4 v = *(const float4*)&src[(size_t)(k0 + kr) * Dn + n0 + 4 * c4];
    ushort4 u;
    u.x = f2b(v.x); u.y = f2b(v.y); u.z = f2b(v.z); u.w = f2b(v.w);
    *(ushort4*)&Tl[kr][4 * c4] = u;
  }
  __syncthreads();
#pragma unroll
  for (int i = 0; i < 4; ++i) {
    int q = tid + 256 * i;
    int nr = q >> 4, c4 = q & 15;
    ushort4 u;
    u.x = Tl[4 * c4 + 0][nr]; u.y = Tl[4 * c4 + 1][nr];
    u.z = Tl[4 * c4 + 2][nr]; u.w = Tl[4 * c4 + 3][nr];
    *(ushort4*)&d[(size_t)(n0 + nr) * Dn + k0 + 4 * c4] = u;
  }
}

// ---------------- prepass: Mt[h][e][k] = 0.125*(I + alpha_h*T_h)[k][e] -----
__global__ __launch_bounds__(256) void k_mkM(const float* __restrict__ tr,
                                             const float* __restrict__ alph,
                                             unsigned short* __restrict__ Mt) {
  int h = blockIdx.x;
  float a = alph[h] * 0.125f;
  const float* th = tr + (size_t)h * DKn * DKn;
  unsigned short* mh = Mt + (size_t)h * DKn * DKn;
  for (int i = threadIdx.x; i < DKn * DKn; i += 256) {
    int e = i >> 6, k = i & 63;
    float v = a * th[(size_t)k * DKn + e] + ((e == k) ? 0.125f : 0.f);
    mh[i] = f2b(v);
  }
}

// ---------------- prepass: Wexp[64][256] -> WexpT[256][64] bf16 ------------
__global__ __launch_bounds__(256) void k_trE(const float* __restrict__ Wexp,
                                             unsigned short* __restrict__ WexpT) {
  int e0 = blockIdx.x * 64;
  __shared__ unsigned short Tl[64][72];
  int tid = threadIdx.x;
#pragma unroll
  for (int i = 0; i < 4; ++i) {
    int q = tid + 256 * i;
    int dr = q >> 4, c4 = q & 15;
    float4 v = *(const float4*)&Wexp[(size_t)dr * EDn + e0 + 4 * c4];
    ushort4 u;
    u.x = f2b(v.x); u.y = f2b(v.y); u.z = f2b(v.z); u.w = f2b(v.w);
    *(ushort4*)&Tl[dr][4 * c4] = u;
  }
  __syncthreads();
#pragma unroll
  for (int i = 0; i < 4; ++i) {
    int q = tid + 256 * i;
    int er = q >> 4, c4 = q & 15;
    ushort4 u;
    u.x = Tl[4 * c4 + 0][er]; u.y = Tl[4 * c4 + 1][er];
    u.z = Tl[4 * c4 + 2][er]; u.w = Tl[4 * c4 + 3][er];
    *(ushort4*)&WexpT[(size_t)(e0 + er) * DKn + 4 * c4] = u;
  }
}

// ---------------- prepass: vtr[h][256][64] -> VTt[h][64][256] bf16 ---------
__global__ __launch_bounds__(256) void k_trVT(const float* __restrict__ vtr,
                                              unsigned short* __restrict__ VTt) {
  int e0 = blockIdx.x * 64;
  int h = blockIdx.y;
  const float* src = vtr + (size_t)h * EDn * DKn;
  unsigned short* dst = VTt + (size_t)h * DKn * EDn;
  __shared__ unsigned short Tl[64][72];
  int tid = threadIdx.x;
#pragma unroll
  for (int i = 0; i < 4; ++i) {
    int q = tid + 256 * i;
    int er = q >> 4, c4 = q & 15;
    float4 v = *(const float4*)&src[(size_t)(e0 + er) * DKn + 4 * c4];
    ushort4 u;
    u.x = f2b(v.x); u.y = f2b(v.y); u.z = f2b(v.z); u.w = f2b(v.w);
    *(ushort4*)&Tl[er][4 * c4] = u;
  }
  __syncthreads();
#pragma unroll
  for (int i = 0; i < 4; ++i) {
    int q = tid + 256 * i;
    int dr = q >> 4, c4 = q & 15;
    ushort4 u;
    u.x = Tl[4 * c4 + 0][dr]; u.y = Tl[4 * c4 + 1][dr];
    u.z = Tl[4 * c4 + 2][dr]; u.w = Tl[4 * c4 + 3][dr];
    *(ushort4*)&dst[(size_t)dr * EDn + e0 + 4 * c4] = u;
  }
}

// ---------------- prepass: x fp32 -> bf16 ----------------------------------
__global__ __launch_bounds__(256) void k_xb(const float* __restrict__ x,
                                            unsigned short* __restrict__ xb) {
  size_t i = ((size_t)blockIdx.x * 256 + threadIdx.x) * 4;
  float4 v = *(const float4*)&x[i];
  ushort4 u;
  u.x = f2b(v.x); u.y = f2b(v.y); u.z = f2b(v.z); u.w = f2b(v.w);
  *(ushort4*)&xb[i] = u;
}

// ---------------- tiny: linv = 1/(l0+l1) -----------------------------------
__global__ __launch_bounds__(256) void k_linv(const float* __restrict__ lbuf,
                                              float* __restrict__ linv) {
  const int BHS = Bn * Hn * Sn;
  int i = blockIdx.x * 256 + threadIdx.x;
  linv[i] = 1.f / (lbuf[i] + lbuf[BHS + i]);
}

// ---------------- MFMA GEMM: 128x128, BK=32, async LDS staging -------------
// MODE 1 additionally fuses the split-S attention combine into A-staging:
// A = AT_ps + (O0 + O1) * linv[row,h].
template <int MODE>
__global__ __launch_bounds__(256) void k_gemm(
    const unsigned short* __restrict__ Ab, const float* __restrict__ Af,
    const unsigned short* __restrict__ BtBase, unsigned short* __restrict__ Qb,
    unsigned short* __restrict__ Kb, unsigned short* __restrict__ VtOut,
    float* __restrict__ Cout, const float* __restrict__ O0g,
    const float* __restrict__ O1g, const float* __restrict__ linvp) {
  const int z = (MODE == 0) ? blockIdx.z : 0;
  const unsigned short* Bt = BtBase + (size_t)z * Dn * Dn;
  __shared__ unsigned short As[128 * 32];
  __shared__ unsigned short Bs[128 * 32];
  const int tid = threadIdx.x;
  const int w = tid >> 6, lane = tid & 63, qd = lane >> 4, cc = lane & 15;
  const int m0 = blockIdx.y * 128, n0 = blockIdx.x * 128;
  const int mW = 64 * (w >> 1), nW = 64 * (w & 1);
  const int srow = lane >> 2;                       // 0..15
  const int schk = 8 * ((lane & 3) ^ (srow & 3));   // swizzled source chunk
  const int r0 = 32 * w + srow, r1 = r0 + 16;
  fvec4 acc[4][4];
#pragma unroll
  for (int i = 0; i < 4; ++i)
#pragma unroll
    for (int j = 0; j < 4; ++j) acc[i][j] = (fvec4){0.f, 0.f, 0.f, 0.f};

  for (int k0 = 0; k0 < Dn; k0 += 32) {
    if (MODE == 0) {
      g2l(&Ab[(size_t)(m0 + r0) * Dn + k0 + schk], &As[1024 * w]);
      g2l(&Ab[(size_t)(m0 + r1) * Dn + k0 + schk], &As[1024 * w + 512]);
    } else {
#pragma unroll
      for (int i = 0; i < 4; ++i) {
        int q = tid + 256 * i;
        int row = q >> 3, c4 = q & 7;
        int gr = m0 + row;
        size_t idx = (size_t)gr * Dn + k0 + 4 * c4;
        float4 ps = *(const float4*)&Af[idx];
        float4 o0 = *(const float4*)&O0g[idx];
        float4 o1 = *(const float4*)&O1g[idx];
        int bb = gr >> 11, ss = gr & 2047;
        int hh = (k0 + 4 * c4) >> 6;
        float li = linvp[(size_t)(bb * Hn + hh) * Sn + ss];
        float4 v;
        v.x = fmaf(o0.x + o1.x, li, ps.x);
        v.y = fmaf(o0.y + o1.y, li, ps.y);
        v.z = fmaf(o0.z + o1.z, li, ps.z);
        v.w = fmaf(o0.w + o1.w, li, ps.w);
        ushort4 u;
        u.x = f2b(v.x); u.y = f2b(v.y); u.z = f2b(v.z); u.w = f2b(v.w);
        *(ushort4*)&As[row * 32 + 8 * ((c4 >> 1) ^ (row & 3)) + 4 * (c4 & 1)] =
            u;
      }
    }
    g2l(&Bt[(size_t)(n0 + r0) * Dn + k0 + schk], &Bs[1024 * w]);
    g2l(&Bt[(size_t)(n0 + r1) * Dn + k0 + schk], &Bs[1024 * w + 512]);
    __syncthreads();
    bvec8 af[4], bf[4];
#pragma unroll
    for (int i = 0; i < 4; ++i) {
      int ra = mW + 16 * i + cc;
      af[i] = *(const bvec8*)&As[ra * 32 + 8 * (qd ^ (ra & 3))];
      int rb = nW + 16 * i + cc;
      bf[i] = *(const bvec8*)&Bs[rb * 32 + 8 * (qd ^ (rb & 3))];
    }
#pragma unroll
    for (int i = 0; i < 4; ++i)
#pragma unroll
      for (int j = 0; j < 4; ++j) acc[i][j] = MFMA(af[i], bf[j], acc[i][j]);
    __syncthreads();
  }
#pragma unroll
  for (int i = 0; i < 4; ++i)
#pragma unroll
    for (int j = 0; j < 4; ++j) {
      int rowb = m0 + mW + 16 * i + 4 * qd;
      int col = n0 + nW + 16 * j + cc;
      if (MODE == 0) {
        int b = rowb >> 11, s = rowb & 2047;
        int h = col >> 6, dk = col & 63;
        if (z == 2) {
          ushort4 u;
          u.x = f2b(acc[i][j][0]); u.y = f2b(acc[i][j][1]);
          u.z = f2b(acc[i][j][2]); u.w = f2b(acc[i][j][3]);
          *(ushort4*)&VtOut[(((size_t)(b * Hn + h)) * DKn + dk) * Sn + s] = u;
        } else {
          unsigned short* Cb = (z == 0) ? Qb : Kb;
#pragma unroll
          for (int r = 0; r < 4; ++r)
            Cb[(((size_t)(b * Hn + h)) * Sn + s + r) * DKn + dk] =
                f2b(acc[i][j][r]);
        }
      } else {
#pragma unroll
        for (int r = 0; r < 4; ++r)
          Cout[(size_t)(rowb + r) * Dn + col] = acc[i][j][r];
      }
    }
}

// ---------------- pattern separation: thin blocks, L2-resident tables ------
// (round-8 version, best known)
__global__ __launch_bounds__(256, 4) void k_pattsep(
    const unsigned short* __restrict__ Qb,
    const unsigned short* __restrict__ WexpT,  // [256][64] bf16
    const unsigned short* __restrict__ VTt,    // [16][64][256] bf16
    const float* __restrict__ alphas, float* __restrict__ AT) {
  __shared__ uint4 Ps4[4][256];
  const int tile = blockIdx.x, bh = blockIdx.y;
  const int b = bh >> 4, h = bh & 15;
  const int tid = threadIdx.x;
  const int w = tid >> 6, lane = tid & 63, qd = lane >> 4, cc = lane & 15;
  const float avt = alphas[16 + h];

  const unsigned short* vtab = VTt + (size_t)h * DKn * EDn;  // [64][256]
  unsigned short* Pw = (unsigned short*)Ps4[w];

  const int s0 = tile * 64 + w * 16;
  bvec8 aq0 = {}, aq1 = {};
  const int srow = s0 + cc;
  if (srow > 0) {
    const unsigned short* qp = Qb + ((size_t)bh * Sn + srow - 1) * DKn;
    aq0 = *(const bvec8*)&qp[8 * qd];
    aq1 = *(const bvec8*)&qp[32 + 8 * qd];
  }
  fvec4 E[16];
#pragma unroll
  for (int j = 0; j < 16; ++j) {
    const int e = 16 * j + cc;
    const unsigned short* wr = WexpT + (size_t)e * 64;  // global, L2-hot
    bvec8 b0 = *(const bvec8*)&wr[8 * qd];
    bvec8 b1 = *(const bvec8*)&wr[32 + 8 * qd];
    fvec4 zv = {0.f, 0.f, 0.f, 0.f};
    zv = MFMA(aq0, b0, zv);
    E[j] = MFMA(aq1, b1, zv);
  }
#pragma unroll
  for (int j = 0; j < 16; ++j)
#pragma unroll
    for (int r = 0; r < 4; ++r) E[j][r] = fmaxf(E[j][r], 0.f);

  float thr[4];
#pragma unroll
  for (int r = 0; r < 4; ++r) {
    // wave-uniform msb of the max value -> uniform loop start
    unsigned mx = 0u;
#pragma unroll
    for (int j = 0; j < 16; ++j) {
      unsigned e = __float_as_uint(E[j][r]);
      mx = mx > e ? mx : e;
    }
    mx = dpp_umax16(mx);
    {
      unsigned o = (unsigned)__shfl_xor((int)mx, 16);
      mx = mx > o ? mx : o;
      o = (unsigned)__shfl_xor((int)mx, 32);
      mx = mx > o ? mx : o;
    }
    int bstart = (mx == 0u) ? -1 : (31 - __clz((int)mx));
    bstart = __builtin_amdgcn_readfirstlane(bstart);
    unsigned cur = 0u;
    bool done = false;
    for (int bit = bstart; bit >= 0; --bit) {
      unsigned cand = cur | (1u << bit);
      float t = __uint_as_float(cand);
      int cnt = 0;
#pragma unroll
      for (int j = 0; j < 16; ++j) cnt += (E[j][r] >= t) ? 1 : 0;
      cnt = dpp_sum16(cnt);
      if (!done && cnt >= 32) {
        cur = cand;
        if (cnt == 32) done = true;
      }
      if (__all(done)) break;
    }
    thr[r] = __uint_as_float(cur);
  }

  fvec4 acc2[4];
#pragma unroll
  for (int j2 = 0; j2 < 4; ++j2) acc2[j2] = (fvec4){0.f, 0.f, 0.f, 0.f};

#pragma unroll
  for (int half = 0; half < 2; ++half) {
#pragma unroll
    for (int j = 0; j < 8; ++j) {
      const int jj = j + 8 * half;
#pragma unroll
      for (int r = 0; r < 4; ++r) {
        float v = E[jj][r];
        bool sel = (v >= thr[r]) && (v > 0.f);
        int row = 4 * qd + r;
        int s = 16 * j + cc;
        int ch = (s >> 3) ^ (row & 7);
        Pw[row * 128 + ch * 8 + (s & 7)] = sel ? f2b(v) : (unsigned short)0;
      }
    }
#pragma unroll
    for (int j2 = 0; j2 < 4; ++j2) {
      const int d = 16 * j2 + cc;
      const unsigned short* vr = vtab + (size_t)d * 256;  // global, L2-hot
#pragma unroll
      for (int c = 0; c < 4; ++c) {
        int cg = 4 * (c + 4 * half) + qd;
        bvec8 bv = *(const bvec8*)&vr[8 * cg];
        int ca = 4 * c + qd;
        bvec8 ap = *(const bvec8*)&Pw[cc * 128 + 8 * (ca ^ (cc & 7))];
        acc2[j2] = MFMA(ap, bv, acc2[j2]);
      }
    }
  }
#pragma unroll
  for (int j2 = 0; j2 < 4; ++j2)
#pragma unroll
    for (int r = 0; r < 4; ++r) {
      int row = s0 + 4 * qd + r;
      AT[((size_t)(b * Sn + row)) * Dn + h * DKn + 16 * j2 + cc] =
          avt * acc2[j2][r];
    }
}

// ---------------- flash attention + fused fold, S^T softmax, SPLIT-S -------
// Grid (32 bh, 16 qt, 2 ks): each block handles K-tiles [16ks, 16ks+16).
// Fixed-offset softmax (p = e^(s-16), no running max) => partials combine
// exactly: O = O0+O1, l = l0+l1. Each split stores UNNORMALIZED O (pure
// stores, no AT RMW) + per-row l; k_linv forms 1/(l0+l1); gemm1's A-staging
// does the combine. LDS 48KB (double-buffer) + launch_bounds(256,3) ->
// 3 blocks/CU = 12 waves/CU (was 2 blocks / 8 waves).
__global__ __launch_bounds__(256, 3) void k_attn(
    const unsigned short* __restrict__ Qb, const unsigned short* __restrict__ Kb,
    const unsigned short* __restrict__ Vt, const unsigned short* __restrict__ Mt,
    float* __restrict__ Oacc, float* __restrict__ lbuf) {
  __shared__ unsigned short Kd[2][64 * 64];  // double-buffered, chunk-swizzled
  __shared__ unsigned short Vl[2][64 * 64];
  __shared__ unsigned short Ps[4][32 * 64];  // per-wave: fold scratch, then P
  const int bh = blockIdx.x, qt = blockIdx.y, ks = blockIdx.z;
  const int b = bh >> 4, h = bh & 15;
  const int tid = threadIdx.x;
  const int w = tid >> 6, lane = tid & 63, qd = lane >> 4, cc = lane & 15;
  const float L2E = 1.4426950408889634f;
  const float NB = 23.083120654223414f;  // 16*log2(e)
  const int kt0 = ks * 16;               // first global K-tile of this split

  // fused fold: Q' = Qraw @ M for 32 rows (frags A,B); scratch in Ps[w]
  const unsigned short* qg = Qb + ((size_t)bh * Sn + qt * 128 + w * 32) * DKn;
  const unsigned short* mh = Mt + (size_t)h * DKn * DKn;
  unsigned short* Pw = Ps[w];
  bvec8 mb0[4], mb1[4];
#pragma unroll
  for (int j = 0; j < 4; ++j) {
    mb0[j] = *(const bvec8*)&mh[(size_t)(16 * j + cc) * DKn + 8 * qd];
    mb1[j] = *(const bvec8*)&mh[(size_t)(16 * j + cc) * DKn + 32 + 8 * qd];
  }
#pragma unroll
  for (int f = 0; f < 2; ++f) {
    bvec8 a0 = *(const bvec8*)&qg[(16 * f + cc) * DKn + 8 * qd];
    bvec8 a1 = *(const bvec8*)&qg[(16 * f + cc) * DKn + 32 + 8 * qd];
#pragma unroll
    for (int j = 0; j < 4; ++j) {
      fvec4 zz = {0.f, 0.f, 0.f, 0.f};
      zz = MFMA(a0, mb0[j], zz);
      zz = MFMA(a1, mb1[j], zz);
#pragma unroll
      for (int r = 0; r < 4; ++r) {
        int qr = 16 * f + 4 * qd + r;
        Pw[qr * 64 + 8 * ((2 * j + (cc >> 3)) ^ (qr & 7)) + (cc & 7)] =
            f2b(zz[r]);
      }
    }
  }
  bvec8 aqA0 = *(const bvec8*)&Pw[cc * 64 + 8 * (qd ^ (cc & 7))];
  bvec8 aqA1 = *(const bvec8*)&Pw[cc * 64 + 8 * ((qd + 4) ^ (cc & 7))];
  bvec8 aqB0 = *(const bvec8*)&Pw[(16 + cc) * 64 + 8 * (qd ^ (cc & 7))];
  bvec8 aqB1 = *(const bvec8*)&Pw[(16 + cc) * 64 + 8 * ((qd + 4) ^ (cc & 7))];

  float lsA = 0.f, lsB = 0.f;  // softmax denominators for q = cc (A), 16+cc (B)
  fvec4 OA[4], OB[4];
#pragma unroll
  for (int j = 0; j < 4; ++j) {
    OA[j] = (fvec4){0.f, 0.f, 0.f, 0.f};
    OB[j] = (fvec4){0.f, 0.f, 0.f, 0.f};
  }

  const int vrow = lane >> 3;                       // 0..7
  const int vchk = 8 * ((lane & 7) ^ (vrow & 7));   // swizzled source chunk
  const unsigned short* kgb = Kb + (size_t)bh * Sn * DKn;
  const unsigned short* vgb = Vt + (size_t)bh * DKn * Sn;

  __builtin_amdgcn_sched_barrier(0);
  // prefetch first tile of this split into buffer 0
  {
    const unsigned short* kg = kgb + (size_t)kt0 * 64 * DKn;
    g2l(&kg[(size_t)(16 * w + vrow) * 64 + vchk], &Kd[0][1024 * w]);
    g2l(&kg[(size_t)(16 * w + 8 + vrow) * 64 + vchk], &Kd[0][1024 * w + 512]);
    g2l(&vgb[(size_t)(16 * w + vrow) * Sn + kt0 * 64 + vchk], &Vl[0][1024 * w]);
    g2l(&vgb[(size_t)(16 * w + 8 + vrow) * Sn + kt0 * 64 + vchk],
        &Vl[0][1024 * w + 512]);
  }

  const int NTs = 16;
  for (int kt = 0; kt < NTs; ++kt) {
    const int buf = kt & 1;
    asm volatile("s_waitcnt vmcnt(0)" ::: "memory");
    __builtin_amdgcn_s_barrier();
    if (kt + 1 < NTs) {  // issue next tile; overlaps this tile's compute
      const int gkt = kt0 + kt + 1;
      const unsigned short* kg = kgb + (size_t)gkt * 64 * DKn;
      unsigned short* Kn = Kd[buf ^ 1];
      unsigned short* Vn = Vl[buf ^ 1];
      g2l(&kg[(size_t)(16 * w + vrow) * 64 + vchk], &Kn[1024 * w]);
      g2l(&kg[(size_t)(16 * w + 8 + vrow) * 64 + vchk], &Kn[1024 * w + 512]);
      g2l(&vgb[(size_t)(16 * w + vrow) * Sn + gkt * 64 + vchk], &Vn[1024 * w]);
      g2l(&vgb[(size_t)(16 * w + 8 + vrow) * Sn + gkt * 64 + vchk],
          &Vn[1024 * w + 512]);
    }
    __builtin_amdgcn_sched_barrier(0);  // keep the issue ahead of compute
    const unsigned short* Kc = Kd[buf];
    const unsigned short* Vc = Vl[buf];
    // S^T: rows = k-cols 16j+4qd+r, col = q. One K-frag feeds both q-frags.
    fvec4 sA[4], sB[4];
#pragma unroll
    for (int j = 0; j < 4; ++j) {
      int rk = 16 * j + cc;
      bvec8 b0 = *(const bvec8*)&Kc[rk * 64 + 8 * (qd ^ (cc & 7))];
      bvec8 b1 = *(const bvec8*)&Kc[rk * 64 + 8 * ((qd + 4) ^ (cc & 7))];
      fvec4 z0 = {0.f, 0.f, 0.f, 0.f};
      z0 = MFMA(b0, aqA0, z0);
      sA[j] = MFMA(b1, aqA1, z0);
      fvec4 z1 = {0.f, 0.f, 0.f, 0.f};
      z1 = MFMA(b0, aqB0, z1);
      sB[j] = MFMA(b1, aqB1, z1);
    }
    // fixed-offset softmax: p = e^(s-16); common factor cancels in O/l.
#pragma unroll
    for (int j = 0; j < 4; ++j) {
      float p0 = __builtin_amdgcn_exp2f(fmaf(sA[j][0], L2E, -NB));
      float p1 = __builtin_amdgcn_exp2f(fmaf(sA[j][1], L2E, -NB));
      float p2 = __builtin_amdgcn_exp2f(fmaf(sA[j][2], L2E, -NB));
      float p3 = __builtin_amdgcn_exp2f(fmaf(sA[j][3], L2E, -NB));
      lsA += (p0 + p1) + (p2 + p3);
      unsigned q01, q23;
      asm("v_cvt_pk_bf16_f32 %0, %1, %2" : "=v"(q01) : "v"(p0), "v"(p1));
      asm("v_cvt_pk_bf16_f32 %0, %1, %2" : "=v"(q23) : "v"(p2), "v"(p3));
      uint2 uu;
      uu.x = q01; uu.y = q23;
      *(uint2*)&Pw[cc * 64 + 4 * ((4 * j + qd) ^ cc)] = uu;
    }
#pragma unroll
    for (int j = 0; j < 4; ++j) {
      float p0 = __builtin_amdgcn_exp2f(fmaf(sB[j][0], L2E, -NB));
      float p1 = __builtin_amdgcn_exp2f(fmaf(sB[j][1], L2E, -NB));
      float p2 = __builtin_amdgcn_exp2f(fmaf(sB[j][2], L2E, -NB));
      float p3 = __builtin_amdgcn_exp2f(fmaf(sB[j][3], L2E, -NB));
      lsB += (p0 + p1) + (p2 + p3);
      unsigned q01, q23;
      asm("v_cvt_pk_bf16_f32 %0, %1, %2" : "=v"(q01) : "v"(p0), "v"(p1));
      asm("v_cvt_pk_bf16_f32 %0, %1, %2" : "=v"(q23) : "v"(p2), "v"(p3));
      uint2 uu;
      uu.x = q01; uu.y = q23;
      *(uint2*)&Pw[(16 + cc) * 64 + 4 * ((4 * j + qd) ^ cc)] = uu;
    }
    // read back A fragments for PV (k=8qd..+7 / 32+8qd..+7 per frag)
    union U16 { bvec8 v; uint2 u[2]; } UA0, UA1, UB0, UB1;
    UA0.u[0] = *(const uint2*)&Pw[cc * 64 + 4 * ((2 * qd) ^ cc)];
    UA0.u[1] = *(const uint2*)&Pw[cc * 64 + 4 * ((2 * qd + 1) ^ cc)];
    UA1.u[0] = *(const uint2*)&Pw[cc * 64 + 4 * ((8 + 2 * qd) ^ cc)];
    UA1.u[1] = *(const uint2*)&Pw[cc * 64 + 4 * ((9 + 2 * qd) ^ cc)];
    UB0.u[0] = *(const uint2*)&Pw[(16 + cc) * 64 + 4 * ((2 * qd) ^ cc)];
    UB0.u[1] = *(const uint2*)&Pw[(16 + cc) * 64 + 4 * ((2 * qd + 1) ^ cc)];
    UB1.u[0] = *(const uint2*)&Pw[(16 + cc) * 64 + 4 * ((8 + 2 * qd) ^ cc)];
    UB1.u[1] = *(const uint2*)&Pw[(16 + cc) * 64 + 4 * ((9 + 2 * qd) ^ cc)];
    // PV: one V-frag feeds both q-frags
#pragma unroll
    for (int j = 0; j < 4; ++j) {
      int rv = 16 * j + cc;
      bvec8 v0 = *(const bvec8*)&Vc[rv * 64 + 8 * (qd ^ (cc & 7))];
      bvec8 v1 = *(const bvec8*)&Vc[rv * 64 + 8 * ((qd + 4) ^ (cc & 7))];
      OA[j] = MFMA(UA0.v, v0, OA[j]);
      OA[j] = MFMA(UA1.v, v1, OA[j]);
      OB[j] = MFMA(UB0.v, v0, OB[j]);
      OB[j] = MFMA(UB1.v, v1, OB[j]);
    }
  }
  // complete l (sum 4 quad partials); store UNNORMALIZED partials
  lsA += __shfl_xor(lsA, 16);
  lsA += __shfl_xor(lsA, 32);
  lsB += __shfl_xor(lsB, 16);
  lsB += __shfl_xor(lsB, 32);
  float* Op = Oacc + (size_t)ks * ((size_t)Bn * Sn * Dn);
#pragma unroll
  for (int j = 0; j < 4; ++j)
#pragma unroll
    for (int r = 0; r < 4; ++r) {
      int rowA = qt * 128 + w * 32 + 4 * qd + r;
      size_t idx = ((size_t)(b * Sn + rowA)) * Dn + h * DKn + 16 * j + cc;
      Op[idx] = OA[j][r];
      Op[idx + 16 * (size_t)Dn] = OB[j][r];
    }
  if (lane < 16) {  // qd==0 lanes: one writer per q-row
    int rb = qt * 128 + w * 32;
    size_t lix = ((size_t)ks * Bn * Hn + b * Hn + h) * Sn + rb + cc;
    lbuf[lix] = lsA;
    lbuf[lix + 16] = lsB;
  }
}

// ---------------- launch ----------------
extern "C" void kernel_launch(void* const* d_in, const int* in_sizes, int n_in,
                              void* d_out, int out_size, void* d_ws,
                              size_t ws_size, hipStream_t stream) {
  const float* x = (const float*)d_in[0];
  const float* Wq = (const float*)d_in[1];
  const float* Wk = (const float*)d_in[2];
  const float* Wv = (const float*)d_in[3];
  const float* Wo = (const float*)d_in[4];
  const float* traces = (const float*)d_in[5];
  const float* vtr = (const float*)d_in[6];
  const float* Wexp = (const float*)d_in[7];

  const size_t NQ = (size_t)Bn * Hn * Sn * DKn;  // 4,194,304
  const size_t NSD = (size_t)Bn * Sn * Dn;       // 4,194,304 floats
  const size_t BHS = (size_t)Bn * Hn * Sn;       // 65,536
  unsigned short* Qb = (unsigned short*)d_ws;
  unsigned short* Kb = Qb + NQ;
  unsigned short* Vt = Kb + NQ;                // (bh, dk, s) bf16
  unsigned short* Wt = Vt + NQ;                // 4 x D*D bf16 = NQ shorts
  unsigned short* Mt = Wt + NQ;                // 16*64*64 = 65536
  unsigned short* WexpT = Mt + 65536;          // 256*64 = 16384
  unsigned short* VTt = WexpT + 16384;         // 16*64*256 = 262144
  float* alph = (float*)(VTt + 262144);        // 32 floats
  float* AT = alph + 32;                       // pattsep term, 16MB
  float* Oacc = AT + NSD;                      // 2 x 16MB unnormalized O
  float* lbuf = Oacc + 2 * NSD;                // 2 x 65536 floats
  float* linv = lbuf + 2 * BHS;                // 65536 floats
  unsigned short* xb = (unsigned short*)AT;    // aliased: dead before pattsep

  k_alphas<<<32, 256, 0, stream>>>(traces, vtr, alph);
  k_trW<<<dim3(16, 16, 4), 256, 0, stream>>>(Wq, Wk, Wv, Wo, Wt);
  k_mkM<<<16, 256, 0, stream>>>(traces, alph, Mt);
  k_trE<<<4, 256, 0, stream>>>(Wexp, WexpT);
  k_trVT<<<dim3(4, 16), 256, 0, stream>>>(vtr, VTt);
  k_xb<<<4096, 256, 0, stream>>>(x, xb);
  k_gemm<0><<<dim3(8, 32, 3), 256, 0, stream>>>(xb, nullptr, Wt, Qb, Kb, Vt,
                                                nullptr, nullptr, nullptr,
                                                nullptr);
  k_pattsep<<<dim3(32, 32), 256, 0, stream>>>(Qb, WexpT, VTt, alph, AT);
  k_attn<<<dim3(32, 16, 2), 256, 0, stream>>>(Qb, Kb, Vt, Mt, Oacc, lbuf);
  k_linv<<<256, 256, 0, stream>>>(lbuf, linv);
  k_gemm<1><<<dim3(8, 32, 1), 256, 0, stream>>>(
      nullptr, AT, Wt + 3 * (size_t)Dn * Dn, nullptr, nullptr, nullptr,
      (float*)d_out, Oacc, Oacc + NSD, linv);
}

// Round 12
// 276.498 us; speedup vs baseline: 1.1339x; 1.1339x over previous
//
#include <hip/hip_runtime.h>
#include <stdint.h>

#define Bn 2
#define Sn 2048
#define Dn 1024
#define Hn 16
#define DKn 64
#define EDn 256

typedef __attribute__((ext_vector_type(8))) short bvec8;   // 8 bf16 (4 VGPR)
typedef __attribute__((ext_vector_type(4))) float fvec4;   // 4 fp32 acc

#define MFMA(a, b, c) __builtin_amdgcn_mfma_f32_16x16x32_bf16(a, b, c, 0, 0, 0)

__device__ __forceinline__ float b2f(unsigned short u) {
  return __uint_as_float(((unsigned)u) << 16);
}
__device__ __forceinline__ unsigned short f2b(float x) {
  unsigned u = __float_as_uint(x);
  u += 0x7fffu + ((u >> 16) & 1u);
  return (unsigned short)(u >> 16);
}
// async global->LDS, 16B/lane; LDS dest is wave-uniform base + lane*16
__device__ __forceinline__ void g2l(const unsigned short* g, unsigned short* l) {
  __builtin_amdgcn_global_load_lds(
      (const __attribute__((address_space(1))) void*)g,
      (__attribute__((address_space(3))) void*)l, 16, 0, 0);
}
// 16-lane butterfly sum via DPP (xor 15,7,3,1) - pure VALU, no DS latency.
__device__ __forceinline__ int dpp_sum16(int x) {
  x += __builtin_amdgcn_update_dpp(0, x, 0x140, 0xf, 0xf, true);
  x += __builtin_amdgcn_update_dpp(0, x, 0x141, 0xf, 0xf, true);
  x += __builtin_amdgcn_update_dpp(0, x, 0x1B, 0xf, 0xf, true);
  x += __builtin_amdgcn_update_dpp(0, x, 0xB1, 0xf, 0xf, true);
  return x;
}
__device__ __forceinline__ unsigned dpp_umax16(unsigned x) {
  unsigned t;
  t = (unsigned)__builtin_amdgcn_update_dpp(0, (int)x, 0x140, 0xf, 0xf, true);
  x = x > t ? x : t;
  t = (unsigned)__builtin_amdgcn_update_dpp(0, (int)x, 0x141, 0xf, 0xf, true);
  x = x > t ? x : t;
  t = (unsigned)__builtin_amdgcn_update_dpp(0, (int)x, 0x1B, 0xf, 0xf, true);
  x = x > t ? x : t;
  t = (unsigned)__builtin_amdgcn_update_dpp(0, (int)x, 0xB1, 0xf, 0xf, true);
  x = x > t ? x : t;
  return x;
}

// ---------------- alphas: 0.05/(1+||.||_F) ----------------
__global__ __launch_bounds__(256) void k_alphas(
    const float* __restrict__ traces, const float* __restrict__ vtr,
    float* __restrict__ alphas) {
  int blk = blockIdx.x;
  const float* base;
  int n;
  if (blk < 16) { base = traces + blk * DKn * DKn; n = DKn * DKn; }
  else          { base = vtr + (blk - 16) * EDn * DKn; n = EDn * DKn; }
  float s = 0.f;
  for (int i = threadIdx.x; i < n; i += 256) { float v = base[i]; s += v * v; }
  __shared__ float red[256];
  red[threadIdx.x] = s;
  __syncthreads();
  for (int off = 128; off > 0; off >>= 1) {
    if (threadIdx.x < off) red[threadIdx.x] += red[threadIdx.x + off];
    __syncthreads();
  }
  if (threadIdx.x == 0) alphas[blk] = 0.05f / (1.f + sqrtf(red[0]));
}

// ---------------- prepass: W^T -> bf16  (Wt[n][k] = W[k][n]) ----------------
__global__ __launch_bounds__(256) void k_trW(
    const float* __restrict__ w0, const float* __restrict__ w1,
    const float* __restrict__ w2, const float* __restrict__ w3,
    unsigned short* __restrict__ dst) {
  int z = blockIdx.z;
  const float* src = (z == 0) ? w0 : ((z == 1) ? w1 : ((z == 2) ? w2 : w3));
  unsigned short* d = dst + (size_t)z * Dn * Dn;
  __shared__ unsigned short Tl[64][72];
  int tid = threadIdx.x;
  int k0 = blockIdx.y * 64, n0 = blockIdx.x * 64;
#pragma unroll
  for (int i = 0; i < 4; ++i) {
    int q = tid + 256 * i;
    int kr = q >> 4, c4 = q & 15;
    float4 v = *(const float4*)&src[(size_t)(k0 + kr) * Dn + n0 + 4 * c4];
    ushort4 u;
    u.x = f2b(v.x); u.y = f2b(v.y); u.z = f2b(v.z); u.w = f2b(v.w);
    *(ushort4*)&Tl[kr][4 * c4] = u;
  }
  __syncthreads();
#pragma unroll
  for (int i = 0; i < 4; ++i) {
    int q = tid + 256 * i;
    int nr = q >> 4, c4 = q & 15;
    ushort4 u;
    u.x = Tl[4 * c4 + 0][nr]; u.y = Tl[4 * c4 + 1][nr];
    u.z = Tl[4 * c4 + 2][nr]; u.w = Tl[4 * c4 + 3][nr];
    *(ushort4*)&d[(size_t)(n0 + nr) * Dn + k0 + 4 * c4] = u;
  }
}

// ---------------- prepass: Mt[h][e][k] = 0.125*(I + alpha_h*T_h)[k][e] -----
__global__ __launch_bounds__(256) void k_mkM(const float* __restrict__ tr,
                                             const float* __restrict__ alph,
                                             unsigned short* __restrict__ Mt) {
  int h = blockIdx.x;
  float a = alph[h] * 0.125f;
  const float* th = tr + (size_t)h * DKn * DKn;
  unsigned short* mh = Mt + (size_t)h * DKn * DKn;
  for (int i = threadIdx.x; i < DKn * DKn; i += 256) {
    int e = i >> 6, k = i & 63;
    float v = a * th[(size_t)k * DKn + e] + ((e == k) ? 0.125f : 0.f);
    mh[i] = f2b(v);
  }
}

// ---- prepass: merged transposes.  y<16: vtr[h][256][64] -> VTt[h][64][256];
// ---- y==16: Wexp[64][256] -> WexpT[256][64].  Same 64x64 bf16 tile body. --
__global__ __launch_bounds__(256) void k_trVT2(const float* __restrict__ vtr,
                                               const float* __restrict__ Wexp,
                                               unsigned short* __restrict__ VTt,
                                               unsigned short* __restrict__ WexpT) {
  int e0 = blockIdx.x * 64;
  int h = blockIdx.y;
  __shared__ unsigned short Tl[64][72];
  int tid = threadIdx.x;
  if (h < 16) {
    const float* src = vtr + (size_t)h * EDn * DKn;
    unsigned short* dst = VTt + (size_t)h * DKn * EDn;
#pragma unroll
    for (int i = 0; i < 4; ++i) {
      int q = tid + 256 * i;
      int er = q >> 4, c4 = q & 15;
      float4 v = *(const float4*)&src[(size_t)(e0 + er) * DKn + 4 * c4];
      ushort4 u;
      u.x = f2b(v.x); u.y = f2b(v.y); u.z = f2b(v.z); u.w = f2b(v.w);
      *(ushort4*)&Tl[er][4 * c4] = u;
    }
    __syncthreads();
#pragma unroll
    for (int i = 0; i < 4; ++i) {
      int q = tid + 256 * i;
      int dr = q >> 4, c4 = q & 15;
      ushort4 u;
      u.x = Tl[4 * c4 + 0][dr]; u.y = Tl[4 * c4 + 1][dr];
      u.z = Tl[4 * c4 + 2][dr]; u.w = Tl[4 * c4 + 3][dr];
      *(ushort4*)&dst[(size_t)dr * EDn + e0 + 4 * c4] = u;
    }
  } else {
#pragma unroll
    for (int i = 0; i < 4; ++i) {
      int q = tid + 256 * i;
      int dr = q >> 4, c4 = q & 15;
      float4 v = *(const float4*)&Wexp[(size_t)dr * EDn + e0 + 4 * c4];
      ushort4 u;
      u.x = f2b(v.x); u.y = f2b(v.y); u.z = f2b(v.z); u.w = f2b(v.w);
      *(ushort4*)&Tl[dr][4 * c4] = u;
    }
    __syncthreads();
#pragma unroll
    for (int i = 0; i < 4; ++i) {
      int q = tid + 256 * i;
      int er = q >> 4, c4 = q & 15;
      ushort4 u;
      u.x = Tl[4 * c4 + 0][er]; u.y = Tl[4 * c4 + 1][er];
      u.z = Tl[4 * c4 + 2][er]; u.w = Tl[4 * c4 + 3][er];
      *(ushort4*)&WexpT[(size_t)(e0 + er) * DKn + 4 * c4] = u;
    }
  }
}

// ---------------- prepass: x fp32 -> bf16 ----------------------------------
__global__ __launch_bounds__(256) void k_xb(const float* __restrict__ x,
                                            unsigned short* __restrict__ xb) {
  size_t i = ((size_t)blockIdx.x * 256 + threadIdx.x) * 4;
  float4 v = *(const float4*)&x[i];
  ushort4 u;
  u.x = f2b(v.x); u.y = f2b(v.y); u.z = f2b(v.z); u.w = f2b(v.w);
  *(ushort4*)&xb[i] = u;
}

// ---------------- MFMA GEMM: 128x128, BK=32, async LDS staging -------------
// (round-8 form: single-buffered; round-10's dbuf variant was neutral-negative)
template <int MODE>
__global__ __launch_bounds__(256) void k_gemm(
    const unsigned short* __restrict__ Ab, const float* __restrict__ Af,
    const unsigned short* __restrict__ BtBase, unsigned short* __restrict__ Qb,
    unsigned short* __restrict__ Kb, unsigned short* __restrict__ VtOut,
    float* __restrict__ Cout) {
  const int z = (MODE == 0) ? blockIdx.z : 0;
  const unsigned short* Bt = BtBase + (size_t)z * Dn * Dn;
  __shared__ unsigned short As[128 * 32];
  __shared__ unsigned short Bs[128 * 32];
  const int tid = threadIdx.x;
  const int w = tid >> 6, lane = tid & 63, qd = lane >> 4, cc = lane & 15;
  const int m0 = blockIdx.y * 128, n0 = blockIdx.x * 128;
  const int mW = 64 * (w >> 1), nW = 64 * (w & 1);
  const int srow = lane >> 2;                       // 0..15
  const int schk = 8 * ((lane & 3) ^ (srow & 3));   // swizzled source chunk
  const int r0 = 32 * w + srow, r1 = r0 + 16;
  fvec4 acc[4][4];
#pragma unroll
  for (int i = 0; i < 4; ++i)
#pragma unroll
    for (int j = 0; j < 4; ++j) acc[i][j] = (fvec4){0.f, 0.f, 0.f, 0.f};

  for (int k0 = 0; k0 < Dn; k0 += 32) {
    if (MODE == 0) {
      g2l(&Ab[(size_t)(m0 + r0) * Dn + k0 + schk], &As[1024 * w]);
      g2l(&Ab[(size_t)(m0 + r1) * Dn + k0 + schk], &As[1024 * w + 512]);
    } else {
#pragma unroll
      for (int i = 0; i < 4; ++i) {
        int q = tid + 256 * i;
        int row = q >> 3, c4 = q & 7;
        float4 v = *(const float4*)&Af[(size_t)(m0 + row) * Dn + k0 + 4 * c4];
        ushort4 u;
        u.x = f2b(v.x); u.y = f2b(v.y); u.z = f2b(v.z); u.w = f2b(v.w);
        *(ushort4*)&As[row * 32 + 8 * ((c4 >> 1) ^ (row & 3)) + 4 * (c4 & 1)] =
            u;
      }
    }
    g2l(&Bt[(size_t)(n0 + r0) * Dn + k0 + schk], &Bs[1024 * w]);
    g2l(&Bt[(size_t)(n0 + r1) * Dn + k0 + schk], &Bs[1024 * w + 512]);
    __syncthreads();
    bvec8 af[4], bf[4];
#pragma unroll
    for (int i = 0; i < 4; ++i) {
      int ra = mW + 16 * i + cc;
      af[i] = *(const bvec8*)&As[ra * 32 + 8 * (qd ^ (ra & 3))];
      int rb = nW + 16 * i + cc;
      bf[i] = *(const bvec8*)&Bs[rb * 32 + 8 * (qd ^ (rb & 3))];
    }
#pragma unroll
    for (int i = 0; i < 4; ++i)
#pragma unroll
      for (int j = 0; j < 4; ++j) acc[i][j] = MFMA(af[i], bf[j], acc[i][j]);
    __syncthreads();
  }
#pragma unroll
  for (int i = 0; i < 4; ++i)
#pragma unroll
    for (int j = 0; j < 4; ++j) {
      int rowb = m0 + mW + 16 * i + 4 * qd;
      int col = n0 + nW + 16 * j + cc;
      if (MODE == 0) {
        int b = rowb >> 11, s = rowb & 2047;
        int h = col >> 6, dk = col & 63;
        if (z == 2) {
          ushort4 u;
          u.x = f2b(acc[i][j][0]); u.y = f2b(acc[i][j][1]);
          u.z = f2b(acc[i][j][2]); u.w = f2b(acc[i][j][3]);
          *(ushort4*)&VtOut[(((size_t)(b * Hn + h)) * DKn + dk) * Sn + s] = u;
        } else {
          unsigned short* Cb = (z == 0) ? Qb : Kb;
#pragma unroll
          for (int r = 0; r < 4; ++r)
            Cb[(((size_t)(b * Hn + h)) * Sn + s + r) * DKn + dk] =
                f2b(acc[i][j][r]);
        }
      } else {
#pragma unroll
        for (int r = 0; r < 4; ++r)
          Cout[(size_t)(rowb + r) * Dn + col] = acc[i][j][r];
      }
    }
}

// ---------------- pattern separation: thin blocks, L2-resident tables ------
// (round-8 version, best known)
__global__ __launch_bounds__(256, 4) void k_pattsep(
    const unsigned short* __restrict__ Qb,
    const unsigned short* __restrict__ WexpT,  // [256][64] bf16
    const unsigned short* __restrict__ VTt,    // [16][64][256] bf16
    const float* __restrict__ alphas, float* __restrict__ AT) {
  __shared__ uint4 Ps4[4][256];
  const int tile = blockIdx.x, bh = blockIdx.y;
  const int b = bh >> 4, h = bh & 15;
  const int tid = threadIdx.x;
  const int w = tid >> 6, lane = tid & 63, qd = lane >> 4, cc = lane & 15;
  const float avt = alphas[16 + h];

  const unsigned short* vtab = VTt + (size_t)h * DKn * EDn;  // [64][256]
  unsigned short* Pw = (unsigned short*)Ps4[w];

  const int s0 = tile * 64 + w * 16;
  bvec8 aq0 = {}, aq1 = {};
  const int srow = s0 + cc;
  if (srow > 0) {
    const unsigned short* qp = Qb + ((size_t)bh * Sn + srow - 1) * DKn;
    aq0 = *(const bvec8*)&qp[8 * qd];
    aq1 = *(const bvec8*)&qp[32 + 8 * qd];
  }
  fvec4 E[16];
#pragma unroll
  for (int j = 0; j < 16; ++j) {
    const int e = 16 * j + cc;
    const unsigned short* wr = WexpT + (size_t)e * 64;  // global, L2-hot
    bvec8 b0 = *(const bvec8*)&wr[8 * qd];
    bvec8 b1 = *(const bvec8*)&wr[32 + 8 * qd];
    fvec4 zv = {0.f, 0.f, 0.f, 0.f};
    zv = MFMA(aq0, b0, zv);
    E[j] = MFMA(aq1, b1, zv);
  }
#pragma unroll
  for (int j = 0; j < 16; ++j)
#pragma unroll
    for (int r = 0; r < 4; ++r) E[j][r] = fmaxf(E[j][r], 0.f);

  float thr[4];
#pragma unroll
  for (int r = 0; r < 4; ++r) {
    // wave-uniform msb of the max value -> uniform loop start
    unsigned mx = 0u;
#pragma unroll
    for (int j = 0; j < 16; ++j) {
      unsigned e = __float_as_uint(E[j][r]);
      mx = mx > e ? mx : e;
    }
    mx = dpp_umax16(mx);
    {
      unsigned o = (unsigned)__shfl_xor((int)mx, 16);
      mx = mx > o ? mx : o;
      o = (unsigned)__shfl_xor((int)mx, 32);
      mx = mx > o ? mx : o;
    }
    int bstart = (mx == 0u) ? -1 : (31 - __clz((int)mx));
    bstart = __builtin_amdgcn_readfirstlane(bstart);
    unsigned cur = 0u;
    bool done = false;
    for (int bit = bstart; bit >= 0; --bit) {
      unsigned cand = cur | (1u << bit);
      float t = __uint_as_float(cand);
      int cnt = 0;
#pragma unroll
      for (int j = 0; j < 16; ++j) cnt += (E[j][r] >= t) ? 1 : 0;
      cnt = dpp_sum16(cnt);
      if (!done && cnt >= 32) {
        cur = cand;
        if (cnt == 32) done = true;
      }
      if (__all(done)) break;
    }
    thr[r] = __uint_as_float(cur);
  }

  fvec4 acc2[4];
#pragma unroll
  for (int j2 = 0; j2 < 4; ++j2) acc2[j2] = (fvec4){0.f, 0.f, 0.f, 0.f};

#pragma unroll
  for (int half = 0; half < 2; ++half) {
#pragma unroll
    for (int j = 0; j < 8; ++j) {
      const int jj = j + 8 * half;
#pragma unroll
      for (int r = 0; r < 4; ++r) {
        float v = E[jj][r];
        bool sel = (v >= thr[r]) && (v > 0.f);
        int row = 4 * qd + r;
        int s = 16 * j + cc;
        int ch = (s >> 3) ^ (row & 7);
        Pw[row * 128 + ch * 8 + (s & 7)] = sel ? f2b(v) : (unsigned short)0;
      }
    }
#pragma unroll
    for (int j2 = 0; j2 < 4; ++j2) {
      const int d = 16 * j2 + cc;
      const unsigned short* vr = vtab + (size_t)d * 256;  // global, L2-hot
#pragma unroll
      for (int c = 0; c < 4; ++c) {
        int cg = 4 * (c + 4 * half) + qd;
        bvec8 bv = *(const bvec8*)&vr[8 * cg];
        int ca = 4 * c + qd;
        bvec8 ap = *(const bvec8*)&Pw[cc * 128 + 8 * (ca ^ (cc & 7))];
        acc2[j2] = MFMA(ap, bv, acc2[j2]);
      }
    }
  }
#pragma unroll
  for (int j2 = 0; j2 < 4; ++j2)
#pragma unroll
    for (int r = 0; r < 4; ++r) {
      int row = s0 + 4 * qd + r;
      AT[((size_t)(b * Sn + row)) * Dn + h * DKn + 16 * j2 + cc] =
          avt * acc2[j2][r];
    }
}

// ---------------- flash attention + fused fold, S^T softmax ----------------
// (round-7/8 version, best known: triple-buffered K/V, counted vmcnt(4))
__global__ __launch_bounds__(256, 2) void k_attn(
    const unsigned short* __restrict__ Qb, const unsigned short* __restrict__ Kb,
    const unsigned short* __restrict__ Vt, const unsigned short* __restrict__ Mt,
    float* __restrict__ AT) {
  __shared__ unsigned short Kd[3][64 * 64];  // triple-buffered, chunk-swizzled
  __shared__ unsigned short Vl[3][64 * 64];
  __shared__ unsigned short Ps[4][32 * 64];  // per-wave: fold scratch, then P
  const int bh = blockIdx.x, qt = blockIdx.y;
  const int b = bh >> 4, h = bh & 15;
  const int tid = threadIdx.x;
  const int w = tid >> 6, lane = tid & 63, qd = lane >> 4, cc = lane & 15;
  const float L2E = 1.4426950408889634f;
  const float NB = 23.083120654223414f;  // 16*log2(e)

  // fused fold: Q' = Qraw @ M for 32 rows (frags A,B); scratch in Ps[w]
  const unsigned short* qg = Qb + ((size_t)bh * Sn + qt * 128 + w * 32) * DKn;
  const unsigned short* mh = Mt + (size_t)h * DKn * DKn;
  unsigned short* Pw = Ps[w];
  bvec8 mb0[4], mb1[4];
#pragma unroll
  for (int j = 0; j < 4; ++j) {
    mb0[j] = *(const bvec8*)&mh[(size_t)(16 * j + cc) * DKn + 8 * qd];
    mb1[j] = *(const bvec8*)&mh[(size_t)(16 * j + cc) * DKn + 32 + 8 * qd];
  }
#pragma unroll
  for (int f = 0; f < 2; ++f) {
    bvec8 a0 = *(const bvec8*)&qg[(16 * f + cc) * DKn + 8 * qd];
    bvec8 a1 = *(const bvec8*)&qg[(16 * f + cc) * DKn + 32 + 8 * qd];
#pragma unroll
    for (int j = 0; j < 4; ++j) {
      fvec4 zz = {0.f, 0.f, 0.f, 0.f};
      zz = MFMA(a0, mb0[j], zz);
      zz = MFMA(a1, mb1[j], zz);
#pragma unroll
      for (int r = 0; r < 4; ++r) {
        int qr = 16 * f + 4 * qd + r;
        Pw[qr * 64 + 8 * ((2 * j + (cc >> 3)) ^ (qr & 7)) + (cc & 7)] =
            f2b(zz[r]);
      }
    }
  }
  bvec8 aqA0 = *(const bvec8*)&Pw[cc * 64 + 8 * (qd ^ (cc & 7))];
  bvec8 aqA1 = *(const bvec8*)&Pw[cc * 64 + 8 * ((qd + 4) ^ (cc & 7))];
  bvec8 aqB0 = *(const bvec8*)&Pw[(16 + cc) * 64 + 8 * (qd ^ (cc & 7))];
  bvec8 aqB1 = *(const bvec8*)&Pw[(16 + cc) * 64 + 8 * ((qd + 4) ^ (cc & 7))];

  float lsA = 0.f, lsB = 0.f;  // softmax denominators for q = cc (A), 16+cc (B)
  fvec4 OA[4], OB[4];
#pragma unroll
  for (int j = 0; j < 4; ++j) {
    OA[j] = (fvec4){0.f, 0.f, 0.f, 0.f};
    OB[j] = (fvec4){0.f, 0.f, 0.f, 0.f};
  }

  const int vrow = lane >> 3;                       // 0..7
  const int vchk = 8 * ((lane & 7) ^ (vrow & 7));   // swizzled source chunk
  const unsigned short* kgb = Kb + (size_t)bh * Sn * DKn;
  const unsigned short* vgb = Vt + (size_t)bh * DKn * Sn;

  // keep prologue prefetch AFTER the fold's global loads (else the fold's
  // vmcnt waits would drain the prefetch queue)
  __builtin_amdgcn_sched_barrier(0);
  // prefetch tiles 0 and 1 (4 g2l per wave per tile, issue order = tile order)
#pragma unroll
  for (int p = 0; p < 2; ++p) {
    const unsigned short* kg = kgb + (size_t)p * 64 * DKn;
    g2l(&kg[(size_t)(16 * w + vrow) * 64 + vchk], &Kd[p][1024 * w]);
    g2l(&kg[(size_t)(16 * w + 8 + vrow) * 64 + vchk], &Kd[p][1024 * w + 512]);
    g2l(&vgb[(size_t)(16 * w + vrow) * Sn + p * 64 + vchk], &Vl[p][1024 * w]);
    g2l(&vgb[(size_t)(16 * w + 8 + vrow) * Sn + p * 64 + vchk],
        &Vl[p][1024 * w + 512]);
  }

  const int NT = Sn / 64;
  int buf = 0;
  for (int kt = 0; kt < NT; ++kt) {
    // wait: tile kt's 4 loads landed; tile kt+1's 4 may stay in flight.
    asm volatile("s_waitcnt vmcnt(4)" ::: "memory");
    __builtin_amdgcn_s_barrier();
    if (kt + 2 < NT) {  // issue tile kt+2 into the buffer freed by kt-1
      int nb = buf + 2;
      if (nb >= 3) nb -= 3;
      const unsigned short* kg = kgb + (size_t)(kt + 2) * 64 * DKn;
      unsigned short* Kn = Kd[nb];
      unsigned short* Vn = Vl[nb];
      g2l(&kg[(size_t)(16 * w + vrow) * 64 + vchk], &Kn[1024 * w]);
      g2l(&kg[(size_t)(16 * w + 8 + vrow) * 64 + vchk], &Kn[1024 * w + 512]);
      g2l(&vgb[(size_t)(16 * w + vrow) * Sn + (kt + 2) * 64 + vchk],
          &Vn[1024 * w]);
      g2l(&vgb[(size_t)(16 * w + 8 + vrow) * Sn + (kt + 2) * 64 + vchk],
          &Vn[1024 * w + 512]);
    }
    __builtin_amdgcn_sched_barrier(0);  // keep the issue ahead of compute
    const unsigned short* Kc = Kd[buf];
    const unsigned short* Vc = Vl[buf];
    // S^T: rows = k-cols 16j+4qd+r, col = q. One K-frag feeds both q-frags.
    fvec4 sA[4], sB[4];
#pragma unroll
    for (int j = 0; j < 4; ++j) {
      int rk = 16 * j + cc;
      bvec8 b0 = *(const bvec8*)&Kc[rk * 64 + 8 * (qd ^ (cc & 7))];
      bvec8 b1 = *(const bvec8*)&Kc[rk * 64 + 8 * ((qd + 4) ^ (cc & 7))];
      fvec4 z0 = {0.f, 0.f, 0.f, 0.f};
      z0 = MFMA(b0, aqA0, z0);
      sA[j] = MFMA(b1, aqA1, z0);
      fvec4 z1 = {0.f, 0.f, 0.f, 0.f};
      z1 = MFMA(b0, aqB0, z1);
      sB[j] = MFMA(b1, aqB1, z1);
    }
    // fixed-offset softmax: p = e^(s-16); common factor cancels in O/l.
#pragma unroll
    for (int j = 0; j < 4; ++j) {
      float p0 = __builtin_amdgcn_exp2f(fmaf(sA[j][0], L2E, -NB));
      float p1 = __builtin_amdgcn_exp2f(fmaf(sA[j][1], L2E, -NB));
      float p2 = __builtin_amdgcn_exp2f(fmaf(sA[j][2], L2E, -NB));
      float p3 = __builtin_amdgcn_exp2f(fmaf(sA[j][3], L2E, -NB));
      lsA += (p0 + p1) + (p2 + p3);
      unsigned q01, q23;
      asm("v_cvt_pk_bf16_f32 %0, %1, %2" : "=v"(q01) : "v"(p0), "v"(p1));
      asm("v_cvt_pk_bf16_f32 %0, %1, %2" : "=v"(q23) : "v"(p2), "v"(p3));
      uint2 uu;
      uu.x = q01; uu.y = q23;
      *(uint2*)&Pw[cc * 64 + 4 * ((4 * j + qd) ^ cc)] = uu;
    }
#pragma unroll
    for (int j = 0; j < 4; ++j) {
      float p0 = __builtin_amdgcn_exp2f(fmaf(sB[j][0], L2E, -NB));
      float p1 = __builtin_amdgcn_exp2f(fmaf(sB[j][1], L2E, -NB));
      float p2 = __builtin_amdgcn_exp2f(fmaf(sB[j][2], L2E, -NB));
      float p3 = __builtin_amdgcn_exp2f(fmaf(sB[j][3], L2E, -NB));
      lsB += (p0 + p1) + (p2 + p3);
      unsigned q01, q23;
      asm("v_cvt_pk_bf16_f32 %0, %1, %2" : "=v"(q01) : "v"(p0), "v"(p1));
      asm("v_cvt_pk_bf16_f32 %0, %1, %2" : "=v"(q23) : "v"(p2), "v"(p3));
      uint2 uu;
      uu.x = q01; uu.y = q23;
      *(uint2*)&Pw[(16 + cc) * 64 + 4 * ((4 * j + qd) ^ cc)] = uu;
    }
    // read back A fragments for PV (k=8qd..+7 / 32+8qd..+7 per frag)
    union U16 { bvec8 v; uint2 u[2]; } UA0, UA1, UB0, UB1;
    UA0.u[0] = *(const uint2*)&Pw[cc * 64 + 4 * ((2 * qd) ^ cc)];
    UA0.u[1] = *(const uint2*)&Pw[cc * 64 + 4 * ((2 * qd + 1) ^ cc)];
    UA1.u[0] = *(const uint2*)&Pw[cc * 64 + 4 * ((8 + 2 * qd) ^ cc)];
    UA1.u[1] = *(const uint2*)&Pw[cc * 64 + 4 * ((9 + 2 * qd) ^ cc)];
    UB0.u[0] = *(const uint2*)&Pw[(16 + cc) * 64 + 4 * ((2 * qd) ^ cc)];
    UB0.u[1] = *(const uint2*)&Pw[(16 + cc) * 64 + 4 * ((2 * qd + 1) ^ cc)];
    UB1.u[0] = *(const uint2*)&Pw[(16 + cc) * 64 + 4 * ((8 + 2 * qd) ^ cc)];
    UB1.u[1] = *(const uint2*)&Pw[(16 + cc) * 64 + 4 * ((9 + 2 * qd) ^ cc)];
    // PV: one V-frag feeds both q-frags
#pragma unroll
    for (int j = 0; j < 4; ++j) {
      int rv = 16 * j + cc;
      bvec8 v0 = *(const bvec8*)&Vc[rv * 64 + 8 * (qd ^ (cc & 7))];
      bvec8 v1 = *(const bvec8*)&Vc[rv * 64 + 8 * ((qd + 4) ^ (cc & 7))];
      OA[j] = MFMA(UA0.v, v0, OA[j]);
      OA[j] = MFMA(UA1.v, v1, OA[j]);
      OB[j] = MFMA(UB0.v, v0, OB[j]);
      OB[j] = MFMA(UB1.v, v1, OB[j]);
    }
    buf = (buf == 2) ? 0 : buf + 1;
  }
  // complete l (sum 4 quad partials), fetch per-row inv, accumulate into AT
  lsA += __shfl_xor(lsA, 16);
  lsA += __shfl_xor(lsA, 32);
  lsB += __shfl_xor(lsB, 16);
  lsB += __shfl_xor(lsB, 32);
  float liA = 1.f / lsA, liB = 1.f / lsB;
  float iA[4], iB[4];
#pragma unroll
  for (int r = 0; r < 4; ++r) {
    iA[r] = __shfl(liA, 4 * qd + r);
    iB[r] = __shfl(liB, 4 * qd + r);
  }
#pragma unroll
  for (int j = 0; j < 4; ++j)
#pragma unroll
    for (int r = 0; r < 4; ++r) {
      int rowA = qt * 128 + w * 32 + 4 * qd + r;
      float* pA = AT + ((size_t)(b * Sn + rowA)) * Dn + h * DKn + 16 * j + cc;
      *pA += OA[j][r] * iA[r];
      float* pB = pA + 16 * (size_t)Dn;
      *pB += OB[j][r] * iB[r];
    }
}

// ---------------- launch ----------------
extern "C" void kernel_launch(void* const* d_in, const int* in_sizes, int n_in,
                              void* d_out, int out_size, void* d_ws,
                              size_t ws_size, hipStream_t stream) {
  const float* x = (const float*)d_in[0];
  const float* Wq = (const float*)d_in[1];
  const float* Wk = (const float*)d_in[2];
  const float* Wv = (const float*)d_in[3];
  const float* Wo = (const float*)d_in[4];
  const float* traces = (const float*)d_in[5];
  const float* vtr = (const float*)d_in[6];
  const float* Wexp = (const float*)d_in[7];

  const size_t NQ = (size_t)Bn * Hn * Sn * DKn;  // 4,194,304
  unsigned short* Qb = (unsigned short*)d_ws;
  unsigned short* Kb = Qb + NQ;
  unsigned short* Vt = Kb + NQ;                // (bh, dk, s) bf16
  unsigned short* Wt = Vt + NQ;                // 4 x D*D bf16 = NQ shorts
  unsigned short* Mt = Wt + NQ;                // 16*64*64 = 65536
  unsigned short* WexpT = Mt + 65536;          // 256*64 = 16384
  unsigned short* VTt = WexpT + 16384;         // 16*64*256 = 262144
  float* alph = (float*)(VTt + 262144);        // 32 floats
  float* AT = alph + 32;                       // (B,S,D) fp32, 16MB
  unsigned short* xb = (unsigned short*)AT;    // aliased: dead before pattsep

  k_alphas<<<32, 256, 0, stream>>>(traces, vtr, alph);
  k_trW<<<dim3(16, 16, 4), 256, 0, stream>>>(Wq, Wk, Wv, Wo, Wt);
  k_mkM<<<16, 256, 0, stream>>>(traces, alph, Mt);
  k_trVT2<<<dim3(4, 17), 256, 0, stream>>>(vtr, Wexp, VTt, WexpT);
  k_xb<<<4096, 256, 0, stream>>>(x, xb);
  k_gemm<0><<<dim3(8, 32, 3), 256, 0, stream>>>(xb, nullptr, Wt, Qb, Kb, Vt,
                                                nullptr);
  k_pattsep<<<dim3(32, 32), 256, 0, stream>>>(Qb, WexpT, VTt, alph, AT);
  k_attn<<<dim3(32, 16), 256, 0, stream>>>(Qb, Kb, Vt, Mt, AT);
  k_gemm<1><<<dim3(8, 32, 1), 256, 0, stream>>>(
      nullptr, AT, Wt + 3 * (size_t)Dn * Dn, nullptr, nullptr, nullptr,
      (float*)d_out);
}